// Round 2
// baseline (4539.671 us; speedup 1.0000x reference)
//
#include <hip/hip_runtime.h>
#include <hip/hip_bf16.h>

#define Nn 8192
#define Tt 32
#define Ff 16
#define Hh 128
#define HEADS 4
#define Ee 2048
#define NNZ 65536
#define TF (Tt*Ff)       // 512
#define G3 (3*Hh)        // 384
#define BN_EPS 1e-5f

// All float tensors are float32 per the reference (jnp.float32 everywhere).
// R0's bf16 misread produced NaN (f32 low half-words decode to bf16 NaN ~0.4%).

// ---------------- static scratch (fully rewritten every call) ----------------
__device__ float g_inx[Nn*TF];          // bn1 output (N, T*F)
__device__ float g_hs[Tt*Nn*Hh];        // GRU hidden states, layout (T, N, H)
__device__ float g_nf[Nn*Hh];           // attention output (f32 master copy)
__device__ float g_xbn[Nn*Hh];          // bn2 output
__device__ float g_ef[Ee*Hh];           // edge feats layer1
__device__ float g_xw[Nn*4*Hh];         // x @ W1^T
__device__ float g_ew[Ee*4*Hh];         // ef @ W1^T
__device__ float g_alpha[NNZ*HEADS];
__device__ float g_alphaN[NNZ*HEADS];
__device__ float g_eout[Ee*4*Hh];
__device__ float g_x1[Nn*Hh];
__device__ float g_ef2[Ee*Hh];
__device__ float g_xw2[Nn*Hh];
__device__ float g_ew2[Ee*Hh];
__device__ float g_alpha2[NNZ];
__device__ float g_alphaN2[NNZ];
__device__ float g_eout2[Ee*Hh];
__device__ float g_x2[Nn*Hh];
__device__ float g_bn1s[TF], g_bn1b[TF];
__device__ float g_bn2s[Hh], g_bn2b[Hh];
__device__ int   g_D[Nn];
__device__ int   g_rowptr[Nn+1];
__device__ int   g_cursor[Nn];
__device__ int   g_eidx[NNZ];

// ---------------- batchnorm 1 ----------------
__global__ __launch_bounds__(256) void bn1_stats(const float* __restrict__ x,
                                                 const float* __restrict__ g,
                                                 const float* __restrict__ b){
  int c = blockIdx.x;  // 0..511
  float s = 0.f, s2 = 0.f;
  for(int n = threadIdx.x; n < Nn; n += 256){
    float v = x[n*TF + c]; s += v; s2 += v*v;
  }
  __shared__ float sh[256], sh2[256];
  sh[threadIdx.x] = s; sh2[threadIdx.x] = s2; __syncthreads();
  for(int o = 128; o > 0; o >>= 1){
    if(threadIdx.x < o){ sh[threadIdx.x] += sh[threadIdx.x+o]; sh2[threadIdx.x] += sh2[threadIdx.x+o]; }
    __syncthreads();
  }
  if(threadIdx.x == 0){
    float m = sh[0]/(float)Nn;
    float v = sh2[0]/(float)Nn - m*m; if(v < 0.f) v = 0.f;
    float rs = rsqrtf(v + BN_EPS);
    float sc = g[c]*rs;
    g_bn1s[c] = sc; g_bn1b[c] = b[c] - m*sc;
  }
}

__global__ __launch_bounds__(256) void bn1_apply(const float* __restrict__ x){
  int i = blockIdx.x*256 + threadIdx.x;
  if(i < Nn*TF){
    int c = i & (TF-1);
    g_inx[i] = x[i]*g_bn1s[c] + g_bn1b[c];
  }
}

// ---------------- GRU ----------------
__global__ __launch_bounds__(256) void gru_step(int t, const float* __restrict__ Wih,
                                                const float* __restrict__ Whh,
                                                const float* __restrict__ bih,
                                                const float* __restrict__ bhh){
  __shared__ float shH[64][Hh+1];  // +1 pad: lanes hit distinct banks
  __shared__ float shX[64][Ff+1];
  int n0 = blockIdx.x*64;
  for(int idx = threadIdx.x; idx < 64*Hh; idx += 256){
    int nl = idx >> 7, k = idx & 127;
    shH[nl][k] = (t == 0) ? 0.f : g_hs[(t-1)*Nn*Hh + (n0+nl)*Hh + k];
  }
  for(int idx = threadIdx.x; idx < 64*Ff; idx += 256){
    int nl = idx >> 4, f = idx & 15;
    shX[nl][f] = g_inx[(n0+nl)*TF + t*Ff + f];
  }
  __syncthreads();
  int nl = threadIdx.x & 63;
  int wv = threadIdx.x >> 6;   // wave id 0..3; h is wave-uniform -> W loads broadcast via sgpr
  for(int jj = 0; jj < 32; ++jj){
    int h = wv*32 + jj;
    const float* wr = Whh + h*Hh;
    const float* wz = Whh + (Hh+h)*Hh;
    const float* wn = Whh + (2*Hh+h)*Hh;
    float hr = bhh[h], hz = bhh[Hh+h], hn = bhh[2*Hh+h];
    #pragma unroll 8
    for(int k = 0; k < Hh; k++){
      float hv = shH[nl][k];
      hr += hv*wr[k]; hz += hv*wz[k]; hn += hv*wn[k];
    }
    const float* ur = Wih + h*Ff;
    const float* uz = Wih + (Hh+h)*Ff;
    const float* un = Wih + (2*Hh+h)*Ff;
    float xr = bih[h], xz = bih[Hh+h], xn = bih[2*Hh+h];
    #pragma unroll
    for(int f = 0; f < Ff; f++){
      float xv = shX[nl][f];
      xr += xv*ur[f]; xz += xv*uz[f]; xn += xv*un[f];
    }
    float r  = 1.f/(1.f + expf(-(xr+hr)));
    float z  = 1.f/(1.f + expf(-(xz+hz)));
    float nn = tanhf(xn + r*hn);
    float hnew = (1.f - z)*nn + z*shH[nl][h];
    g_hs[t*Nn*Hh + (n0+nl)*Hh + h] = hnew;
  }
}

// ---------------- temporal attention (fused per node) ----------------
__global__ __launch_bounds__(128) void attn_fused(const float* __restrict__ Wq, const float* __restrict__ Wout,
                                                  const float* __restrict__ ae, const float* __restrict__ ab,
                                                  float* __restrict__ out_nf){
  int n = blockIdx.x, tid = threadIdx.x;
  __shared__ float shHt[Hh], shQ[Hh], shW[Tt], shM[Hh];
  shHt[tid] = g_hs[(Tt-1)*Nn*Hh + n*Hh + tid];
  __syncthreads();
  float q = 0.f;
  const float* wq = Wq + tid*Hh;
  for(int k = 0; k < Hh; k++) q += wq[k]*shHt[k];
  shQ[tid] = q; __syncthreads();
  if(tid < Tt){
    float sc = 0.f;
    const float* ctx = g_hs + tid*Nn*Hh + n*Hh;
    for(int h = 0; h < Hh; h++) sc += shQ[h]*ctx[h];
    shW[tid] = sc;
  }
  __syncthreads();
  if(tid == 0){
    float m = -1e30f;
    for(int t = 0; t < Tt; t++) m = fmaxf(m, shW[t]);
    float s = 0.f;
    for(int t = 0; t < Tt; t++){ float e2 = expf(shW[t]-m); shW[t] = e2; s += e2; }
    float inv = 1.f/s;
    for(int t = 0; t < Tt; t++) shW[t] *= inv;
  }
  __syncthreads();
  float aev = ae[n], abv = ab[n];
  float acc = 0.f;
  for(int t = 0; t < Tt; t++){
    float mix = shW[t]*g_hs[t*Nn*Hh + n*Hh + tid];
    float bt  = expf(-abv*(float)(Tt-1-t));
    float t2  = aev*mix*bt; if(t2 < 0.f) t2 = 0.f;   // relu
    acc += mix + t2;
  }
  shM[tid] = acc; __syncthreads();
  float o = 0.f;
  const float* wo = Wout + tid*2*Hh;
  for(int k = 0; k < Hh; k++) o += wo[k]*shM[k];
  for(int k = 0; k < Hh; k++) o += wo[Hh+k]*shQ[k];
  float nf = tanhf(o);
  g_nf[n*Hh+tid] = nf;
  out_nf[n*Hh+tid] = nf;
}

// ---------------- batchnorm 2 ----------------
__global__ __launch_bounds__(256) void bn2_stats(const float* __restrict__ g, const float* __restrict__ b){
  int c = blockIdx.x;  // 0..127
  float s = 0.f, s2 = 0.f;
  for(int n = threadIdx.x; n < Nn; n += 256){
    float v = g_nf[n*Hh + c]; s += v; s2 += v*v;
  }
  __shared__ float sh[256], sh2[256];
  sh[threadIdx.x] = s; sh2[threadIdx.x] = s2; __syncthreads();
  for(int o = 128; o > 0; o >>= 1){
    if(threadIdx.x < o){ sh[threadIdx.x] += sh[threadIdx.x+o]; sh2[threadIdx.x] += sh2[threadIdx.x+o]; }
    __syncthreads();
  }
  if(threadIdx.x == 0){
    float m = sh[0]/(float)Nn;
    float v = sh2[0]/(float)Nn - m*m; if(v < 0.f) v = 0.f;
    float rs = rsqrtf(v + BN_EPS);
    float sc = g[c]*rs;
    g_bn2s[c] = sc; g_bn2b[c] = b[c] - m*sc;
  }
}

__global__ __launch_bounds__(256) void bn2_apply(){
  int i = blockIdx.x*256 + threadIdx.x;
  if(i < Nn*Hh){
    int c = i & (Hh-1);
    g_xbn[i] = g_nf[i]*g_bn2s[c] + g_bn2b[c];
  }
}

// ---------------- CSR over src ----------------
__global__ __launch_bounds__(256) void zero_D(){
  int i = blockIdx.x*256 + threadIdx.x;
  if(i < Nn) g_D[i] = 0;
}
__global__ __launch_bounds__(256) void count_src(const int* __restrict__ e){
  int i = blockIdx.x*256 + threadIdx.x;
  if(i < NNZ) atomicAdd(&g_D[e[i]], 1);
}
__global__ __launch_bounds__(256) void scan_D(){
  __shared__ int part[256];
  int tid = threadIdx.x;
  int s = 0;
  for(int j = 0; j < 32; j++) s += g_D[tid*32 + j];
  part[tid] = s; __syncthreads();
  if(tid == 0){
    int run = 0;
    for(int i = 0; i < 256; i++){ int v = part[i]; part[i] = run; run += v; }
    g_rowptr[Nn] = run;
  }
  __syncthreads();
  int off = part[tid];
  for(int j = 0; j < 32; j++){
    int idx = tid*32 + j;
    g_rowptr[idx] = off; g_cursor[idx] = off;
    off += g_D[idx];
  }
}
__global__ __launch_bounds__(256) void fill_csr(const int* __restrict__ e){
  int i = blockIdx.x*256 + threadIdx.x;
  if(i < NNZ){
    int pos = atomicAdd(&g_cursor[e[i]], 1);
    g_eidx[pos] = i;
  }
}

// ---------------- edge feats: members of edge d are i = d + k*E (dst = tile(arange(E),32)) ----------------
__global__ __launch_bounds__(128) void edge_gather_sum(const int* __restrict__ e, int which){
  const float* x = which ? g_x1 : g_xbn;
  float* ef      = which ? g_ef2 : g_ef;
  __shared__ int srcs[32];
  int d = blockIdx.x;
  if(threadIdx.x < 32) srcs[threadIdx.x] = e[d + threadIdx.x*Ee];
  __syncthreads();
  int c = threadIdx.x;
  float acc = 0.f;
  for(int k = 0; k < 32; k++) acc += x[srcs[k]*Hh + c];
  ef[d*Hh + c] = acc;
}

// ---------------- generic C[M][Nc] = A[M][128] * W[Nc][128]^T ----------------
__global__ __launch_bounds__(256) void matmul_wT(const float* __restrict__ W, int sel){
  const float* A; float* C; int Nc;
  if(sel == 0){ A = g_xbn; C = g_xw;  Nc = 512; }
  else if(sel == 1){ A = g_ef;  C = g_ew;  Nc = 512; }
  else if(sel == 2){ A = g_x1;  C = g_xw2; Nc = 128; }
  else { A = g_ef2; C = g_ew2; Nc = 128; }
  __shared__ float As[64][65];
  __shared__ float Ws[64][65];
  int bm = blockIdx.x*64, bn = blockIdx.y*64;
  int tc = threadIdx.x & 15, tr = threadIdx.x >> 4;
  float acc[4][4] = {};
  for(int kt = 0; kt < 2; kt++){
    __syncthreads();
    for(int idx = threadIdx.x; idx < 64*64; idx += 256){
      int r = idx >> 6, c = idx & 63;
      As[r][c] = A[(bm+r)*Hh + kt*64 + c];
      Ws[r][c] = W[(bn+r)*Hh + kt*64 + c];
    }
    __syncthreads();
    for(int k = 0; k < 64; k++){
      float av[4], wv[4];
      #pragma unroll
      for(int a = 0; a < 4; a++) av[a] = As[tr*4+a][k];
      #pragma unroll
      for(int b = 0; b < 4; b++) wv[b] = Ws[tc*4+b][k];
      #pragma unroll
      for(int a = 0; a < 4; a++)
        #pragma unroll
        for(int b = 0; b < 4; b++) acc[a][b] += av[a]*wv[b];
    }
  }
  for(int a = 0; a < 4; a++)
    for(int b = 0; b < 4; b++)
      C[(bm+tr*4+a)*Nc + bn + tc*4+b] = acc[a][b];
}

// ---------------- attention coefficients ----------------
__global__ __launch_bounds__(256) void alpha1_k(const int* __restrict__ e, const float* __restrict__ att1){
  __shared__ float a1s[HEADS*2*Hh];  // 1024 floats
  for(int k = threadIdx.x; k < HEADS*2*Hh; k += 256) a1s[k] = att1[k];
  __syncthreads();
  int idx = blockIdx.x*256 + threadIdx.x;
  if(idx >= NNZ*HEADS) return;
  int i = idx >> 2, hd = idx & 3;
  int s = e[i], d = e[NNZ + i];
  const float* xr = g_xw + s*512 + hd*128;
  const float* er = g_ew + d*512 + hd*128;
  const float* a1 = a1s + hd*256;
  float acc = 0.f;
  for(int k = 0; k < 128; k++) acc += xr[k]*a1[k] + er[k]*a1[128+k];
  g_alpha[i*HEADS + hd] = (acc >= 0.f) ? acc : 0.2f*acc;   // leaky 0.2
}

__global__ __launch_bounds__(256) void alpha2_k(const int* __restrict__ e, const float* __restrict__ att2){
  __shared__ float a2s[2*Hh];
  for(int k = threadIdx.x; k < 2*Hh; k += 256) a2s[k] = att2[k];
  __syncthreads();
  int i = blockIdx.x*256 + threadIdx.x;
  if(i >= NNZ) return;
  int s = e[i], d = e[NNZ + i];
  const float* xr = g_xw2 + s*Hh;
  const float* er = g_ew2 + d*Hh;
  float acc = 0.f;
  for(int k = 0; k < Hh; k++) acc += xr[k]*a2s[k] + er[k]*a2s[Hh+k];
  g_alpha2[i] = (acc >= 0.f) ? acc : 0.2f*acc;
}

// ---------------- per-src-segment softmax (deterministic via CSR) ----------------
__global__ __launch_bounds__(64) void seg_softmax_k(int sel){
  const float* alpha = sel ? g_alpha2 : g_alpha;
  float* alphaN      = sel ? g_alphaN2 : g_alphaN;
  int heads          = sel ? 1 : HEADS;
  int n = blockIdx.x, lane = threadIdx.x;
  int start = g_rowptr[n], deg = g_rowptr[n+1] - start;
  for(int hd = 0; hd < heads; hd++){
    float m = -1e30f;
    for(int base = 0; base < deg; base += 64){
      int j = base + lane;
      float v = (j < deg) ? alpha[g_eidx[start+j]*heads + hd] : -1e30f;
      m = fmaxf(m, v);
    }
    for(int o = 32; o > 0; o >>= 1) m = fmaxf(m, __shfl_xor(m, o));
    float s = 0.f;
    for(int base = 0; base < deg; base += 64){
      int j = base + lane;
      if(j < deg){
        int ei = g_eidx[start+j];
        float ex2 = expf(alpha[ei*heads + hd] - m);
        alphaN[ei*heads + hd] = ex2;
        s += ex2;
      }
    }
    for(int o = 32; o > 0; o >>= 1) s += __shfl_xor(s, o);
    float inv = 1.f/(s + 1e-16f);
    for(int base = 0; base < deg; base += 64){
      int j = base + lane;
      if(j < deg) alphaN[g_eidx[start+j]*heads + hd] *= inv;
    }
  }
}

// ---------------- hconv aggregation ----------------
__global__ __launch_bounds__(256) void eout1_k(const int* __restrict__ e){
  __shared__ int srcs[32];
  __shared__ float al[32][HEADS];
  int d = blockIdx.x;
  if(threadIdx.x < 32) srcs[threadIdx.x] = e[d + threadIdx.x*Ee];
  if(threadIdx.x < 128){
    int k = threadIdx.x >> 2, hd = threadIdx.x & 3;
    al[k][hd] = g_alphaN[(d + k*Ee)*HEADS + hd];
  }
  __syncthreads();
  for(int o = threadIdx.x; o < 512; o += 256){
    int hd = o >> 7, c = o & 127;
    float acc = 0.f;
    for(int k = 0; k < 32; k++) acc += al[k][hd]*g_xw[srcs[k]*512 + hd*128 + c];
    g_eout[d*512 + o] = acc*(1.f/32.f);   // Binv = 1/32 (B=32 by construction)
  }
}

__global__ __launch_bounds__(128) void node_out1(const int* __restrict__ e, const float* __restrict__ bias1){
  int n = blockIdx.x, c = threadIdx.x;
  int start = g_rowptr[n], deg = g_rowptr[n+1] - start;
  float acc = 0.f;
  for(int j = 0; j < deg; j++){
    int i = g_eidx[start+j];
    int d = e[NNZ + i];
    const float* er = g_eout + d*512;
    float a0 = g_alphaN[i*4+0], a1 = g_alphaN[i*4+1], a2 = g_alphaN[i*4+2], a3 = g_alphaN[i*4+3];
    acc += a0*er[c] + a1*er[128+c] + a2*er[256+c] + a3*er[384+c];
  }
  float Dinv = (deg > 0) ? 1.f/(float)deg : 0.f;
  float v = acc*Dinv*0.25f + bias1[c];            // mean over 4 heads + bias
  g_x1[n*Hh + c] = (v >= 0.f) ? v : 0.2f*v;       // leaky 0.2 (hg_attn)
}

__global__ __launch_bounds__(128) void eout2_k(const int* __restrict__ e){
  __shared__ int srcs[32];
  __shared__ float al[32];
  int d = blockIdx.x;
  if(threadIdx.x < 32){
    srcs[threadIdx.x] = e[d + threadIdx.x*Ee];
    al[threadIdx.x]   = g_alphaN2[d + threadIdx.x*Ee];
  }
  __syncthreads();
  int c = threadIdx.x;
  float acc = 0.f;
  for(int k = 0; k < 32; k++) acc += al[k]*g_xw2[srcs[k]*Hh + c];
  g_eout2[d*Hh + c] = acc*(1.f/32.f);
}

__global__ __launch_bounds__(128) void node_out2(const int* __restrict__ e, const float* __restrict__ bias2,
                                                 float* __restrict__ out_x){
  int n = blockIdx.x, c = threadIdx.x;
  int start = g_rowptr[n], deg = g_rowptr[n+1] - start;
  float acc = 0.f;
  for(int j = 0; j < deg; j++){
    int i = g_eidx[start+j];
    int d = e[NNZ + i];
    acc += g_alphaN2[i]*g_eout2[d*Hh + c];
  }
  float Dinv = (deg > 0) ? 1.f/(float)deg : 0.f;
  float v = acc*Dinv + bias2[c];
  v = (v >= 0.f) ? v : 0.2f*v;                    // leaky 0.2 (hg_attn)
  g_x2[n*Hh + c] = v;
  out_x[n*Hh + c] = v;
}

// ---------------- final projection ----------------
__global__ __launch_bounds__(128) void final_k(const float* __restrict__ Wo, const float* __restrict__ bo,
                                               float* __restrict__ outp){
  int n = blockIdx.x;
  __shared__ float sh[128];
  sh[threadIdx.x] = g_x2[n*Hh + threadIdx.x]*Wo[threadIdx.x];
  __syncthreads();
  for(int o = 64; o > 0; o >>= 1){
    if(threadIdx.x < o) sh[threadIdx.x] += sh[threadIdx.x+o];
    __syncthreads();
  }
  if(threadIdx.x == 0){
    float r = sh[0] + bo[0];
    r = (r >= 0.f) ? r : 0.01f*r;                 // leaky 0.01
    outp[n] = r;
  }
}

extern "C" void kernel_launch(void* const* d_in, const int* in_sizes, int n_in,
                              void* d_out, int out_size, void* d_ws, size_t ws_size,
                              hipStream_t stream){
  const float* price = (const float*)d_in[0];
  const int*   e     = (const int*)  d_in[1];
  const float* bn1_g = (const float*)d_in[2];
  const float* bn1_b = (const float*)d_in[3];
  const float* W_ih  = (const float*)d_in[4];
  const float* W_hh  = (const float*)d_in[5];
  const float* b_ih  = (const float*)d_in[6];
  const float* b_hh  = (const float*)d_in[7];
  const float* Wq    = (const float*)d_in[8];
  const float* Wout  = (const float*)d_in[9];
  const float* ae    = (const float*)d_in[10];
  const float* ab    = (const float*)d_in[11];
  const float* bn2_g = (const float*)d_in[12];
  const float* bn2_b = (const float*)d_in[13];
  const float* W1    = (const float*)d_in[14];
  const float* att1  = (const float*)d_in[15];
  const float* bias1 = (const float*)d_in[16];
  const float* W2    = (const float*)d_in[17];
  const float* att2  = (const float*)d_in[18];
  const float* bias2 = (const float*)d_in[19];
  const float* Wo    = (const float*)d_in[20];
  const float* bo    = (const float*)d_in[21];

  float* out_nf = (float*)d_out;
  float* out_x  = out_nf + Nn*Hh;
  float* out_o  = out_nf + 2*Nn*Hh;

  // stage 1: batchnorm1
  bn1_stats<<<TF, 256, 0, stream>>>(price, bn1_g, bn1_b);
  bn1_apply<<<(Nn*TF)/256, 256, 0, stream>>>(price);

  // stage 2: GRU (32 sequential steps)
  for(int t = 0; t < Tt; t++)
    gru_step<<<Nn/64, 256, 0, stream>>>(t, W_ih, W_hh, b_ih, b_hh);

  // stage 3: temporal attention -> nf (output 0)
  attn_fused<<<Nn, 128, 0, stream>>>(Wq, Wout, ae, ab, out_nf);

  // stage 4: batchnorm2
  bn2_stats<<<Hh, 256, 0, stream>>>(bn2_g, bn2_b);
  bn2_apply<<<(Nn*Hh)/256, 256, 0, stream>>>();

  // CSR over src
  zero_D<<<Nn/256, 256, 0, stream>>>();
  count_src<<<NNZ/256, 256, 0, stream>>>(e);
  scan_D<<<1, 256, 0, stream>>>();
  fill_csr<<<NNZ/256, 256, 0, stream>>>(e);

  // hyper-conv layer 1 (heads=4)
  edge_gather_sum<<<Ee, 128, 0, stream>>>(e, 0);
  { dim3 g(Nn/64, 512/64); matmul_wT<<<g, 256, 0, stream>>>(W1, 0); }
  { dim3 g(Ee/64, 512/64); matmul_wT<<<g, 256, 0, stream>>>(W1, 1); }
  alpha1_k<<<(NNZ*HEADS)/256, 256, 0, stream>>>(e, att1);
  seg_softmax_k<<<Nn, 64, 0, stream>>>(0);
  eout1_k<<<Ee, 256, 0, stream>>>(e);
  node_out1<<<Nn, 128, 0, stream>>>(e, bias1);

  // hyper-conv layer 2 (heads=1) -> x (output 1)
  edge_gather_sum<<<Ee, 128, 0, stream>>>(e, 1);
  { dim3 g(Nn/64, 128/64); matmul_wT<<<g, 256, 0, stream>>>(W2, 2); }
  { dim3 g(Ee/64, 128/64); matmul_wT<<<g, 256, 0, stream>>>(W2, 3); }
  alpha2_k<<<NNZ/256, 256, 0, stream>>>(e, att2);
  seg_softmax_k<<<Nn, 64, 0, stream>>>(1);
  eout2_k<<<Ee, 128, 0, stream>>>(e);
  node_out2<<<Nn, 128, 0, stream>>>(e, bias2, out_x);

  // final projection -> out (output 2)
  final_k<<<Nn, 128, 0, stream>>>(Wo, bo, out_o);

  (void)in_sizes; (void)n_in; (void)out_size; (void)d_ws; (void)ws_size;
}

// Round 3
// 652.306 us; speedup vs baseline: 6.9594x; 6.9594x over previous
//
#include <hip/hip_runtime.h>
#include <hip/hip_bf16.h>

#define Nn 8192
#define Tt 32
#define Ff 16
#define Hh 128
#define HEADS 4
#define Ee 2048
#define NNZ 65536
#define TF (Tt*Ff)       // 512
#define G3 (3*Hh)        // 384
#define BN_EPS 1e-5f

// All float tensors are float32 per the reference.

typedef __attribute__((ext_vector_type(8))) short bf8_t;   // 8 bf16 lanes (4 VGPRs)
typedef __attribute__((ext_vector_type(4))) float f4_t;
#define MFMA16(a,b,c) __builtin_amdgcn_mfma_f32_16x16x32_bf16(a,b,c,0,0,0)

__device__ __forceinline__ short f2bf(float v){
  union { __hip_bfloat16 h; short s; } u;
  u.h = __float2bfloat16(v);
  return u.s;
}
__device__ __forceinline__ float bf2f(short s){
  union { __hip_bfloat16 h; short s2; } u;
  u.s2 = s;
  return __bfloat162float(u.h);
}

// ---------------- static scratch (fully rewritten every call) ----------------
__device__ float g_inx[Nn*TF];          // bn1 output (N, T*F)
__device__ float g_hs[Tt*Nn*Hh];        // GRU hidden states, layout (T, N, H)
__device__ float g_q[Nn*Hh];            // query = hT @ Wq^T
__device__ float g_cmb[Nn*2*Hh];        // [mixsum | q] per node
__device__ float g_nf[Nn*Hh];           // attention output (f32 master copy)
__device__ float g_xbn[Nn*Hh];          // bn2 output
__device__ float g_ef[Ee*Hh];           // edge feats layer1
__device__ float g_xw[Nn*4*Hh];         // x @ W1^T
__device__ float g_ew[Ee*4*Hh];         // ef @ W1^T
__device__ float g_alpha[NNZ*HEADS];
__device__ float g_alphaN[NNZ*HEADS];
__device__ float g_eout[Ee*4*Hh];
__device__ float g_x1[Nn*Hh];
__device__ float g_ef2[Ee*Hh];
__device__ float g_xw2[Nn*Hh];
__device__ float g_ew2[Ee*Hh];
__device__ float g_alpha2[NNZ];
__device__ float g_alphaN2[NNZ];
__device__ float g_eout2[Ee*Hh];
__device__ float g_x2[Nn*Hh];
__device__ float g_bn1s[TF], g_bn1b[TF];
__device__ float g_bn2s[Hh], g_bn2b[Hh];
__device__ int   g_D[Nn];
__device__ int   g_rowptr[Nn+1];
__device__ int   g_cursor[Nn];
__device__ int   g_eidx[NNZ];

// ---------------- batchnorm 1 ----------------
__global__ __launch_bounds__(256) void bn1_stats(const float* __restrict__ x,
                                                 const float* __restrict__ g,
                                                 const float* __restrict__ b){
  int c = blockIdx.x;  // 0..511
  float s = 0.f, s2 = 0.f;
  for(int n = threadIdx.x; n < Nn; n += 256){
    float v = x[n*TF + c]; s += v; s2 += v*v;
  }
  __shared__ float sh[256], sh2[256];
  sh[threadIdx.x] = s; sh2[threadIdx.x] = s2; __syncthreads();
  for(int o = 128; o > 0; o >>= 1){
    if(threadIdx.x < o){ sh[threadIdx.x] += sh[threadIdx.x+o]; sh2[threadIdx.x] += sh2[threadIdx.x+o]; }
    __syncthreads();
  }
  if(threadIdx.x == 0){
    float m = sh[0]/(float)Nn;
    float v = sh2[0]/(float)Nn - m*m; if(v < 0.f) v = 0.f;
    float rs = rsqrtf(v + BN_EPS);
    float sc = g[c]*rs;
    g_bn1s[c] = sc; g_bn1b[c] = b[c] - m*sc;
  }
}

__global__ __launch_bounds__(256) void bn1_apply(const float* __restrict__ x){
  int i = blockIdx.x*256 + threadIdx.x;
  if(i < Nn*TF){
    int c = i & (TF-1);
    g_inx[i] = x[i]*g_bn1s[c] + g_bn1b[c];
  }
}

// ---------------- GRU: single persistent kernel, bf16 MFMA ----------------
// Block: 32 nodes, 256 threads (4 waves). Wave w owns col-tiles ct = w+4i, i<6.
// Tile interleave puts each (r,z,n) gate triplet on the SAME lane.
// W frags live in registers across all 32 steps; h state in LDS (f32).
// h operand is hi/lo-split bf16 (compensated); W is bf16 (hi only).
__global__ __launch_bounds__(256) void gru_all(const float* __restrict__ Wih,
                                               const float* __restrict__ Whh,
                                               const float* __restrict__ bih,
                                               const float* __restrict__ bhh){
  __shared__ float shH[32][132];   // padded: +4 keeps b128 reads ~2-way
  __shared__ float shX[32][20];
  int tid = threadIdx.x;
  int w = tid >> 6, lane = tid & 63;
  int nlo = lane & 15, quad = lane >> 4;
  int n0 = blockIdx.x*32;

  for(int i = tid; i < 32*132; i += 256) (&shH[0][0])[i] = 0.f;

  // preload W_hh frags (hi only): B[n=lane&15][k=quad*8+j]
  bf8_t Bh[6][4];
  for(int i = 0; i < 6; i++){
    int c = 16*(w + 4*i) + nlo;
    const float* wr = Whh + c*Hh;
    for(int kk = 0; kk < 4; kk++){
      int k0 = kk*32 + quad*8;
      bf8_t f;
      #pragma unroll
      for(int j = 0; j < 8; j++) f[j] = f2bf(wr[k0 + j]);
      Bh[i][kk] = f;
    }
  }
  // preload W_ih frags (K padded 16->32: quads 2,3 zero)
  bf8_t Bx[6];
  for(int i = 0; i < 6; i++){
    int c = 16*(w + 4*i) + nlo;
    bf8_t f;
    #pragma unroll
    for(int j = 0; j < 8; j++){
      int k = quad*8 + j;
      f[j] = (k < Ff) ? f2bf(Wih[c*Ff + k]) : (short)0;
    }
    Bx[i] = f;
  }
  float biasRZ[4];
  for(int i = 0; i < 4; i++){
    int c = 16*(w + 4*i) + nlo;
    biasRZ[i] = bih[c] + bhh[c];
  }
  float bihn[2], bhhn[2];
  for(int j = 0; j < 2; j++){
    int g = 16*(w + 4*j) + nlo;
    bihn[j] = bih[256 + g];
    bhhn[j] = bhh[256 + g];
  }
  __syncthreads();

  for(int t = 0; t < Tt; t++){
    // stage x tile (32 nodes x 16 features)
    for(int idx = tid; idx < 32*16; idx += 256){
      int nl = idx >> 4, f = idx & 15;
      shX[nl][f] = g_inx[(n0+nl)*TF + t*Ff + f];
    }
    __syncthreads();

    f4_t acc[2][6];    // i<4: r,z (x-part + h-part + bias); i>=4: h-part of n only
    f4_t xnacc[2][2];  // xn (x-part of n, kept separate) + bih_n
    for(int rt = 0; rt < 2; rt++){
      for(int i = 0; i < 4; i++){ f4_t z4; z4[0]=z4[1]=z4[2]=z4[3]=biasRZ[i]; acc[rt][i]=z4; }
      for(int i = 4; i < 6; i++){ f4_t z4; z4[0]=z4[1]=z4[2]=z4[3]=0.f; acc[rt][i]=z4; }
      for(int j = 0; j < 2; j++){ f4_t z4; z4[0]=z4[1]=z4[2]=z4[3]=bihn[j]; xnacc[rt][j]=z4; }
    }

    // x MFMAs (one K-iter, hi/lo compensated)
    for(int rt = 0; rt < 2; rt++){
      bf8_t xhi, xlo;
      if(quad < 2){
        int m = rt*16 + nlo;
        const float* xp = &shX[m][quad*8];
        #pragma unroll
        for(int j = 0; j < 8; j++){
          float v = xp[j];
          short h = f2bf(v);
          xhi[j] = h;
          xlo[j] = f2bf(v - bf2f(h));
        }
      } else {
        #pragma unroll
        for(int j = 0; j < 8; j++){ xhi[j] = 0; xlo[j] = 0; }
      }
      #pragma unroll
      for(int i = 0; i < 4; i++){
        acc[rt][i] = MFMA16(xlo, Bx[i], acc[rt][i]);
        acc[rt][i] = MFMA16(xhi, Bx[i], acc[rt][i]);
      }
      #pragma unroll
      for(int j = 0; j < 2; j++){
        xnacc[rt][j] = MFMA16(xlo, Bx[4+j], xnacc[rt][j]);
        xnacc[rt][j] = MFMA16(xhi, Bx[4+j], xnacc[rt][j]);
      }
    }

    // h MFMAs: A[m=lane&15][k=quad*8+j] from shH, hi/lo split
    for(int kk = 0; kk < 4; kk++){
      bf8_t ahi[2], alo[2];
      for(int rt = 0; rt < 2; rt++){
        int m = rt*16 + nlo;
        const float* hp = &shH[m][kk*32 + quad*8];
        float4 v0 = *(const float4*)hp;
        float4 v1 = *(const float4*)(hp + 4);
        float vv[8] = {v0.x,v0.y,v0.z,v0.w,v1.x,v1.y,v1.z,v1.w};
        #pragma unroll
        for(int j = 0; j < 8; j++){
          float v = vv[j];
          short h = f2bf(v);
          ahi[rt][j] = h;
          alo[rt][j] = f2bf(v - bf2f(h));
        }
      }
      #pragma unroll
      for(int i = 0; i < 6; i++){
        acc[0][i] = MFMA16(alo[0], Bh[i][kk], acc[0][i]);
        acc[0][i] = MFMA16(ahi[0], Bh[i][kk], acc[0][i]);
        acc[1][i] = MFMA16(alo[1], Bh[i][kk], acc[1][i]);
        acc[1][i] = MFMA16(ahi[1], Bh[i][kk], acc[1][i]);
      }
    }

    // gates: C/D layout col=lane&15, row=quad*4+reg
    float hnew[2][2][4];
    for(int rt = 0; rt < 2; rt++)
      for(int j = 0; j < 2; j++){
        int g = 16*(w + 4*j) + nlo;
        for(int rr = 0; rr < 4; rr++){
          int m = rt*16 + quad*4 + rr;
          float r  = 1.f/(1.f + __expf(-acc[rt][j][rr]));
          float z  = 1.f/(1.f + __expf(-acc[rt][2+j][rr]));
          float hn = acc[rt][4+j][rr] + bhhn[j];
          float arg = xnacc[rt][j][rr] + r*hn;
          float nn = 1.f - 2.f/(__expf(2.f*arg) + 1.f);   // tanh
          float ho = shH[m][g];
          float hv = (1.f - z)*nn + z*ho;
          hnew[rt][j][rr] = hv;
          g_hs[(t*Nn + n0 + m)*Hh + g] = hv;
        }
      }
    __syncthreads();   // all reads of shH (frags + h_old) done
    for(int rt = 0; rt < 2; rt++)
      for(int j = 0; j < 2; j++){
        int g = 16*(w + 4*j) + nlo;
        for(int rr = 0; rr < 4; rr++){
          int m = rt*16 + quad*4 + rr;
          shH[m][g] = hnew[rt][j][rr];
        }
      }
    __syncthreads();   // h_new visible for next step
  }
}

// ---------------- generic f32 tile GEMM: C = act(A[M][K] @ B[Nc][K]^T) ----------------
// sel 0: A=g_hs[T-1], C=g_q, K=128  (query projection)
// sel 1: A=g_cmb, C=g_nf (+C2=out_nf), K=256, tanh epilogue
__global__ __launch_bounds__(256) void gemm_f32(const float* __restrict__ B,
                                                float* __restrict__ C2, int sel){
  const float* A; float* C; int K;
  if(sel == 0){ A = g_hs + (Tt-1)*Nn*Hh; C = g_q;  K = 128; }
  else        { A = g_cmb;               C = g_nf; K = 256; }
  __shared__ float As[64][65], Bs[64][65];
  int bm = blockIdx.x*64, bn = blockIdx.y*64;
  int tc = threadIdx.x & 15, tr = threadIdx.x >> 4;
  float acc[4][4] = {};
  for(int kt = 0; kt < K; kt += 64){
    __syncthreads();
    for(int idx = threadIdx.x; idx < 64*64; idx += 256){
      int r = idx >> 6, c = idx & 63;
      As[r][c] = A[(bm+r)*K + kt + c];
      Bs[r][c] = B[(bn+r)*K + kt + c];
    }
    __syncthreads();
    for(int k = 0; k < 64; k++){
      float av[4], wv[4];
      #pragma unroll
      for(int a = 0; a < 4; a++) av[a] = As[tr*4+a][k];
      #pragma unroll
      for(int b = 0; b < 4; b++) wv[b] = Bs[tc*4+b][k];
      #pragma unroll
      for(int a = 0; a < 4; a++)
        #pragma unroll
        for(int b = 0; b < 4; b++) acc[a][b] += av[a]*wv[b];
    }
  }
  for(int a = 0; a < 4; a++)
    for(int b = 0; b < 4; b++){
      float v = acc[a][b];
      if(sel == 1) v = tanhf(v);
      int off = (bm+tr*4+a)*Hh + bn + tc*4 + b;
      C[off] = v;
      if(sel == 1) C2[off] = v;
    }
}

// ---------------- temporal attention middle: scores->softmax->mixsum ----------------
__global__ __launch_bounds__(128) void attn_mid(const float* __restrict__ ae,
                                                const float* __restrict__ ab){
  __shared__ float shHs[32][132];
  __shared__ float shQ[128];
  __shared__ float shSc[32];
  __shared__ float shWt[32];
  int n = blockIdx.x, tid = threadIdx.x;
  for(int idx = tid; idx < 32*128; idx += 128){
    int t = idx >> 7, h = idx & 127;
    shHs[t][h] = g_hs[(t*Nn + n)*Hh + h];
  }
  float vq = g_q[n*Hh + tid];
  shQ[tid] = vq;
  __syncthreads();
  {  // scores: 4 lanes per t
    int g4 = tid >> 2, l4 = tid & 3;
    float s = 0.f;
    for(int h = l4; h < 128; h += 4) s += shQ[h]*shHs[g4][h];
    s += __shfl_xor(s, 1);
    s += __shfl_xor(s, 2);
    if(l4 == 0) shSc[g4] = s;
  }
  __syncthreads();
  if(tid < 64){  // softmax over 32 on wave 0
    float v = (tid < 32) ? shSc[tid] : -1e30f;
    float m = v;
    for(int o = 16; o > 0; o >>= 1) m = fmaxf(m, __shfl_xor(m, o));
    float e2 = (tid < 32) ? __expf(v - m) : 0.f;
    float s = e2;
    for(int o = 16; o > 0; o >>= 1) s += __shfl_xor(s, o);
    if(tid < 32) shWt[tid] = e2/s;
  }
  __syncthreads();
  float aev = ae[n], abv = ab[n];
  float acc = 0.f;
  for(int t = 0; t < 32; t++){
    float mix = shWt[t]*shHs[t][tid];
    float bt  = __expf(-abv*(float)(31 - t));
    float r2  = aev*mix*bt;
    acc += mix + (r2 > 0.f ? r2 : 0.f);
  }
  g_cmb[n*256 + tid] = acc;
  g_cmb[n*256 + 128 + tid] = vq;
}

// ---------------- batchnorm 2 ----------------
__global__ __launch_bounds__(256) void bn2_stats(const float* __restrict__ g, const float* __restrict__ b){
  int c = blockIdx.x;  // 0..127
  float s = 0.f, s2 = 0.f;
  for(int n = threadIdx.x; n < Nn; n += 256){
    float v = g_nf[n*Hh + c]; s += v; s2 += v*v;
  }
  __shared__ float sh[256], sh2[256];
  sh[threadIdx.x] = s; sh2[threadIdx.x] = s2; __syncthreads();
  for(int o = 128; o > 0; o >>= 1){
    if(threadIdx.x < o){ sh[threadIdx.x] += sh[threadIdx.x+o]; sh2[threadIdx.x] += sh2[threadIdx.x+o]; }
    __syncthreads();
  }
  if(threadIdx.x == 0){
    float m = sh[0]/(float)Nn;
    float v = sh2[0]/(float)Nn - m*m; if(v < 0.f) v = 0.f;
    float rs = rsqrtf(v + BN_EPS);
    float sc = g[c]*rs;
    g_bn2s[c] = sc; g_bn2b[c] = b[c] - m*sc;
  }
}

__global__ __launch_bounds__(256) void bn2_apply(){
  int i = blockIdx.x*256 + threadIdx.x;
  if(i < Nn*Hh){
    int c = i & (Hh-1);
    g_xbn[i] = g_nf[i]*g_bn2s[c] + g_bn2b[c];
  }
}

// ---------------- CSR over src ----------------
__global__ __launch_bounds__(256) void zero_D(){
  int i = blockIdx.x*256 + threadIdx.x;
  if(i < Nn) g_D[i] = 0;
}
__global__ __launch_bounds__(256) void count_src(const int* __restrict__ e){
  int i = blockIdx.x*256 + threadIdx.x;
  if(i < NNZ) atomicAdd(&g_D[e[i]], 1);
}
__global__ __launch_bounds__(256) void scan_D(){
  __shared__ int part[256];
  int tid = threadIdx.x;
  int s = 0;
  for(int j = 0; j < 32; j++) s += g_D[tid*32 + j];
  part[tid] = s; __syncthreads();
  if(tid == 0){
    int run = 0;
    for(int i = 0; i < 256; i++){ int v = part[i]; part[i] = run; run += v; }
    g_rowptr[Nn] = run;
  }
  __syncthreads();
  int off = part[tid];
  for(int j = 0; j < 32; j++){
    int idx = tid*32 + j;
    g_rowptr[idx] = off; g_cursor[idx] = off;
    off += g_D[idx];
  }
}
__global__ __launch_bounds__(256) void fill_csr(const int* __restrict__ e){
  int i = blockIdx.x*256 + threadIdx.x;
  if(i < NNZ){
    int pos = atomicAdd(&g_cursor[e[i]], 1);
    g_eidx[pos] = i;
  }
}

// ---------------- edge feats ----------------
__global__ __launch_bounds__(128) void edge_gather_sum(const int* __restrict__ e, int which){
  const float* x = which ? g_x1 : g_xbn;
  float* ef      = which ? g_ef2 : g_ef;
  __shared__ int srcs[32];
  int d = blockIdx.x;
  if(threadIdx.x < 32) srcs[threadIdx.x] = e[d + threadIdx.x*Ee];
  __syncthreads();
  int c = threadIdx.x;
  float acc = 0.f;
  for(int k = 0; k < 32; k++) acc += x[srcs[k]*Hh + c];
  ef[d*Hh + c] = acc;
}

// ---------------- generic C[M][Nc] = A[M][128] * W[Nc][128]^T ----------------
__global__ __launch_bounds__(256) void matmul_wT(const float* __restrict__ W, int sel){
  const float* A; float* C; int Nc;
  if(sel == 0){ A = g_xbn; C = g_xw;  Nc = 512; }
  else if(sel == 1){ A = g_ef;  C = g_ew;  Nc = 512; }
  else if(sel == 2){ A = g_x1;  C = g_xw2; Nc = 128; }
  else { A = g_ef2; C = g_ew2; Nc = 128; }
  __shared__ float As[64][65];
  __shared__ float Ws[64][65];
  int bm = blockIdx.x*64, bn = blockIdx.y*64;
  int tc = threadIdx.x & 15, tr = threadIdx.x >> 4;
  float acc[4][4] = {};
  for(int kt = 0; kt < 2; kt++){
    __syncthreads();
    for(int idx = threadIdx.x; idx < 64*64; idx += 256){
      int r = idx >> 6, c = idx & 63;
      As[r][c] = A[(bm+r)*Hh + kt*64 + c];
      Ws[r][c] = W[(bn+r)*Hh + kt*64 + c];
    }
    __syncthreads();
    for(int k = 0; k < 64; k++){
      float av[4], wv[4];
      #pragma unroll
      for(int a = 0; a < 4; a++) av[a] = As[tr*4+a][k];
      #pragma unroll
      for(int b = 0; b < 4; b++) wv[b] = Ws[tc*4+b][k];
      #pragma unroll
      for(int a = 0; a < 4; a++)
        #pragma unroll
        for(int b = 0; b < 4; b++) acc[a][b] += av[a]*wv[b];
    }
  }
  for(int a = 0; a < 4; a++)
    for(int b = 0; b < 4; b++)
      C[(bm+tr*4+a)*Nc + bn + tc*4+b] = acc[a][b];
}

// ---------------- attention coefficients ----------------
__global__ __launch_bounds__(256) void alpha1_k(const int* __restrict__ e, const float* __restrict__ att1){
  __shared__ float a1s[HEADS*2*Hh];
  for(int k = threadIdx.x; k < HEADS*2*Hh; k += 256) a1s[k] = att1[k];
  __syncthreads();
  int idx = blockIdx.x*256 + threadIdx.x;
  if(idx >= NNZ*HEADS) return;
  int i = idx >> 2, hd = idx & 3;
  int s = e[i], d = e[NNZ + i];
  const float* xr = g_xw + s*512 + hd*128;
  const float* er = g_ew + d*512 + hd*128;
  const float* a1 = a1s + hd*256;
  float acc = 0.f;
  for(int k = 0; k < 128; k++) acc += xr[k]*a1[k] + er[k]*a1[128+k];
  g_alpha[i*HEADS + hd] = (acc >= 0.f) ? acc : 0.2f*acc;
}

__global__ __launch_bounds__(256) void alpha2_k(const int* __restrict__ e, const float* __restrict__ att2){
  __shared__ float a2s[2*Hh];
  for(int k = threadIdx.x; k < 2*Hh; k += 256) a2s[k] = att2[k];
  __syncthreads();
  int i = blockIdx.x*256 + threadIdx.x;
  if(i >= NNZ) return;
  int s = e[i], d = e[NNZ + i];
  const float* xr = g_xw2 + s*Hh;
  const float* er = g_ew2 + d*Hh;
  float acc = 0.f;
  for(int k = 0; k < Hh; k++) acc += xr[k]*a2s[k] + er[k]*a2s[Hh+k];
  g_alpha2[i] = (acc >= 0.f) ? acc : 0.2f*acc;
}

// ---------------- per-src-segment softmax (deterministic via CSR) ----------------
__global__ __launch_bounds__(64) void seg_softmax_k(int sel){
  const float* alpha = sel ? g_alpha2 : g_alpha;
  float* alphaN      = sel ? g_alphaN2 : g_alphaN;
  int heads          = sel ? 1 : HEADS;
  int n = blockIdx.x, lane = threadIdx.x;
  int start = g_rowptr[n], deg = g_rowptr[n+1] - start;
  for(int hd = 0; hd < heads; hd++){
    float m = -1e30f;
    for(int base = 0; base < deg; base += 64){
      int j = base + lane;
      float v = (j < deg) ? alpha[g_eidx[start+j]*heads + hd] : -1e30f;
      m = fmaxf(m, v);
    }
    for(int o = 32; o > 0; o >>= 1) m = fmaxf(m, __shfl_xor(m, o));
    float s = 0.f;
    for(int base = 0; base < deg; base += 64){
      int j = base + lane;
      if(j < deg){
        int ei = g_eidx[start+j];
        float ex2 = expf(alpha[ei*heads + hd] - m);
        alphaN[ei*heads + hd] = ex2;
        s += ex2;
      }
    }
    for(int o = 32; o > 0; o >>= 1) s += __shfl_xor(s, o);
    float inv = 1.f/(s + 1e-16f);
    for(int base = 0; base < deg; base += 64){
      int j = base + lane;
      if(j < deg) alphaN[g_eidx[start+j]*heads + hd] *= inv;
    }
  }
}

// ---------------- hconv aggregation ----------------
__global__ __launch_bounds__(256) void eout1_k(const int* __restrict__ e){
  __shared__ int srcs[32];
  __shared__ float al[32][HEADS];
  int d = blockIdx.x;
  if(threadIdx.x < 32) srcs[threadIdx.x] = e[d + threadIdx.x*Ee];
  if(threadIdx.x < 128){
    int k = threadIdx.x >> 2, hd = threadIdx.x & 3;
    al[k][hd] = g_alphaN[(d + k*Ee)*HEADS + hd];
  }
  __syncthreads();
  for(int o = threadIdx.x; o < 512; o += 256){
    int hd = o >> 7, c = o & 127;
    float acc = 0.f;
    for(int k = 0; k < 32; k++) acc += al[k][hd]*g_xw[srcs[k]*512 + hd*128 + c];
    g_eout[d*512 + o] = acc*(1.f/32.f);   // Binv = 1/32 by construction
  }
}

__global__ __launch_bounds__(128) void node_out1(const int* __restrict__ e, const float* __restrict__ bias1){
  int n = blockIdx.x, c = threadIdx.x;
  int start = g_rowptr[n], deg = g_rowptr[n+1] - start;
  float acc = 0.f;
  for(int j = 0; j < deg; j++){
    int i = g_eidx[start+j];
    int d = e[NNZ + i];
    const float* er = g_eout + d*512;
    float a0 = g_alphaN[i*4+0], a1 = g_alphaN[i*4+1], a2 = g_alphaN[i*4+2], a3 = g_alphaN[i*4+3];
    acc += a0*er[c] + a1*er[128+c] + a2*er[256+c] + a3*er[384+c];
  }
  float Dinv = (deg > 0) ? 1.f/(float)deg : 0.f;
  float v = acc*Dinv*0.25f + bias1[c];
  g_x1[n*Hh + c] = (v >= 0.f) ? v : 0.2f*v;
}

__global__ __launch_bounds__(128) void eout2_k(const int* __restrict__ e){
  __shared__ int srcs[32];
  __shared__ float al[32];
  int d = blockIdx.x;
  if(threadIdx.x < 32){
    srcs[threadIdx.x] = e[d + threadIdx.x*Ee];
    al[threadIdx.x]   = g_alphaN2[d + threadIdx.x*Ee];
  }
  __syncthreads();
  int c = threadIdx.x;
  float acc = 0.f;
  for(int k = 0; k < 32; k++) acc += al[k]*g_xw2[srcs[k]*Hh + c];
  g_eout2[d*Hh + c] = acc*(1.f/32.f);
}

__global__ __launch_bounds__(128) void node_out2(const int* __restrict__ e, const float* __restrict__ bias2,
                                                 float* __restrict__ out_x){
  int n = blockIdx.x, c = threadIdx.x;
  int start = g_rowptr[n], deg = g_rowptr[n+1] - start;
  float acc = 0.f;
  for(int j = 0; j < deg; j++){
    int i = g_eidx[start+j];
    int d = e[NNZ + i];
    acc += g_alphaN2[i]*g_eout2[d*Hh + c];
  }
  float Dinv = (deg > 0) ? 1.f/(float)deg : 0.f;
  float v = acc*Dinv + bias2[c];
  v = (v >= 0.f) ? v : 0.2f*v;
  g_x2[n*Hh + c] = v;
  out_x[n*Hh + c] = v;
}

// ---------------- final projection ----------------
__global__ __launch_bounds__(128) void final_k(const float* __restrict__ Wo, const float* __restrict__ bo,
                                               float* __restrict__ outp){
  int n = blockIdx.x;
  __shared__ float sh[128];
  sh[threadIdx.x] = g_x2[n*Hh + threadIdx.x]*Wo[threadIdx.x];
  __syncthreads();
  for(int o = 64; o > 0; o >>= 1){
    if(threadIdx.x < o) sh[threadIdx.x] += sh[threadIdx.x+o];
    __syncthreads();
  }
  if(threadIdx.x == 0){
    float r = sh[0] + bo[0];
    r = (r >= 0.f) ? r : 0.01f*r;
    outp[n] = r;
  }
}

extern "C" void kernel_launch(void* const* d_in, const int* in_sizes, int n_in,
                              void* d_out, int out_size, void* d_ws, size_t ws_size,
                              hipStream_t stream){
  const float* price = (const float*)d_in[0];
  const int*   e     = (const int*)  d_in[1];
  const float* bn1_g = (const float*)d_in[2];
  const float* bn1_b = (const float*)d_in[3];
  const float* W_ih  = (const float*)d_in[4];
  const float* W_hh  = (const float*)d_in[5];
  const float* b_ih  = (const float*)d_in[6];
  const float* b_hh  = (const float*)d_in[7];
  const float* Wq    = (const float*)d_in[8];
  const float* Wout  = (const float*)d_in[9];
  const float* ae    = (const float*)d_in[10];
  const float* ab    = (const float*)d_in[11];
  const float* bn2_g = (const float*)d_in[12];
  const float* bn2_b = (const float*)d_in[13];
  const float* W1    = (const float*)d_in[14];
  const float* att1  = (const float*)d_in[15];
  const float* bias1 = (const float*)d_in[16];
  const float* W2    = (const float*)d_in[17];
  const float* att2  = (const float*)d_in[18];
  const float* bias2 = (const float*)d_in[19];
  const float* Wo    = (const float*)d_in[20];
  const float* bo    = (const float*)d_in[21];

  float* out_nf = (float*)d_out;
  float* out_x  = out_nf + Nn*Hh;
  float* out_o  = out_nf + 2*Nn*Hh;

  // stage 1: batchnorm1
  bn1_stats<<<TF, 256, 0, stream>>>(price, bn1_g, bn1_b);
  bn1_apply<<<(Nn*TF)/256, 256, 0, stream>>>(price);

  // stage 2: GRU — ONE kernel, 256 blocks (1/CU), MFMA inner loop
  gru_all<<<Nn/32, 256, 0, stream>>>(W_ih, W_hh, b_ih, b_hh);

  // stage 3: temporal attention -> nf (output 0)
  { dim3 g(Nn/64, 2); gemm_f32<<<g, 256, 0, stream>>>(Wq, nullptr, 0); }   // q = hT @ Wq^T
  attn_mid<<<Nn, 128, 0, stream>>>(ae, ab);
  { dim3 g(Nn/64, 2); gemm_f32<<<g, 256, 0, stream>>>(Wout, out_nf, 1); } // tanh(cmb @ Wout^T)

  // stage 4: batchnorm2
  bn2_stats<<<Hh, 256, 0, stream>>>(bn2_g, bn2_b);
  bn2_apply<<<(Nn*Hh)/256, 256, 0, stream>>>();

  // CSR over src
  zero_D<<<Nn/256, 256, 0, stream>>>();
  count_src<<<NNZ/256, 256, 0, stream>>>(e);
  scan_D<<<1, 256, 0, stream>>>();
  fill_csr<<<NNZ/256, 256, 0, stream>>>(e);

  // hyper-conv layer 1 (heads=4)
  edge_gather_sum<<<Ee, 128, 0, stream>>>(e, 0);
  { dim3 g(Nn/64, 512/64); matmul_wT<<<g, 256, 0, stream>>>(W1, 0); }
  { dim3 g(Ee/64, 512/64); matmul_wT<<<g, 256, 0, stream>>>(W1, 1); }
  alpha1_k<<<(NNZ*HEADS)/256, 256, 0, stream>>>(e, att1);
  seg_softmax_k<<<Nn, 64, 0, stream>>>(0);
  eout1_k<<<Ee, 256, 0, stream>>>(e);
  node_out1<<<Nn, 128, 0, stream>>>(e, bias1);

  // hyper-conv layer 2 (heads=1) -> x (output 1)
  edge_gather_sum<<<Ee, 128, 0, stream>>>(e, 1);
  { dim3 g(Nn/64, 128/64); matmul_wT<<<g, 256, 0, stream>>>(W2, 2); }
  { dim3 g(Ee/64, 128/64); matmul_wT<<<g, 256, 0, stream>>>(W2, 3); }
  alpha2_k<<<NNZ/256, 256, 0, stream>>>(e, att2);
  seg_softmax_k<<<Nn, 64, 0, stream>>>(1);
  eout2_k<<<Ee, 128, 0, stream>>>(e);
  node_out2<<<Nn, 128, 0, stream>>>(e, bias2, out_x);

  // final projection -> out (output 2)
  final_k<<<Nn, 128, 0, stream>>>(Wo, bo, out_o);

  (void)in_sizes; (void)n_in; (void)out_size; (void)d_ws; (void)ws_size;
}